// Round 3
// baseline (7732.239 us; speedup 1.0000x reference)
//
#include <hip/hip_runtime.h>
#include <hip/hip_bf16.h>
#include <stdint.h>
#include <stddef.h>

// Problem dims
#define B_    64
#define L_    64
#define T_    15
#define V_    32000
#define E_    512
#define H_    1024
#define ENC_  1024
#define ATT_  512
#define S_    128

// Output layout (f32 elements): logits | dec_log_probs | preds | attns
#define DEC_OFF  30720000   // B*T*V
#define PRED_OFF 30720960   // + B*T
#define ATT_OFF  30721920   // + B*T

// ---------------------------------------------------------------------------
// Generic skinny GEMM, "variant B": CT[n][m] = sum_k W[n][k] * A[k][m]
//   W: [N,K] f32 row-major (global).  A: conceptually [K][64] f32.
//   Block: 256 thr = 4 waves. Block tile: 64 n-rows x 64 m(batch). lane = m.
//   Wave wv handles n = n0 + wv*16 + j (j=0..15) -> acc[16] per lane.
//   K split across blockIdx.z chunks of KB (partials written per z).
// AMODE: 0 = A is f32 [K][64] at AT
//        1 = A is the gathered x vector: emb|style|ctx  (gi GEMM)
//        2 = A is f32 [M,K] row-major at Af (enc_output -> keys_proj)
// OUTMODE: 0 = write f32 Cout[z*zstride + n*c_sn + m*c_sm] (+bias if given)
//          1 = W2 path: fused bias + f32 logits write + online max/sum/argmax
//              partials (pmax/psum/pidx indexed [(bx*4+wv)*64 + lane])
// ---------------------------------------------------------------------------
template<int AMODE, int OUTMODE>
__global__ __launch_bounds__(256) void gemm_b(
    const float* __restrict__ W, int N, int K, int KB,
    const float* __restrict__ AT,
    const float* __restrict__ Af,
    const float* __restrict__ stab,
    const int* __restrict__ previ,
    const int* __restrict__ styles,
    const float* __restrict__ chT,
    const float* __restrict__ bias,
    float* __restrict__ Cout, size_t zstride, int c_sn, int c_sm,
    float* __restrict__ out2, int t,
    float* __restrict__ pmax, float* __restrict__ psum, int* __restrict__ pidx)
{
  __shared__ float Ws[64 * 36];
  const int tid  = threadIdx.x;
  const int lane = tid & 63;
  const int wv   = tid >> 6;
  const int n0   = blockIdx.x * 64;
  const int m0   = blockIdx.y * 64;
  const int kb0  = blockIdx.z * KB;

  long erow = 0, srow = 0;
  if (AMODE == 1) {
    int pv = previ[lane];
    if (pv < 0 || pv >= V_) pv = 0;       // defensive: never fault on a bad argmax
    erow = (long)pv * E_;
    srow = (long)styles[lane] * S_;
  }

  auto xfetch = [&](int k) -> float {
    if (k < E_)            return Af[erow + k];
    else if (k < E_ + S_)  return stab[srow + (k - E_)];
    else                   return chT[(size_t)(k - (E_ + S_)) * 64 + lane];
  };

  float acc[16];
#pragma unroll
  for (int j = 0; j < 16; ++j) acc[j] = 0.f;

  for (int kc = kb0; kc < kb0 + KB; kc += 32) {
    { // stage W chunk [64 n][32 k] -> LDS (padded stride 36)
      int n = tid >> 2, k8 = (tid & 3) * 8;
      const float4* wp = (const float4*)(W + (size_t)(n0 + n) * K + kc + k8);
      float4 u0 = wp[0], u1 = wp[1];
      float* ds = &Ws[n * 36 + k8];
      ds[0] = u0.x; ds[1] = u0.y; ds[2] = u0.z; ds[3] = u0.w;
      ds[4] = u1.x; ds[5] = u1.y; ds[6] = u1.z; ds[7] = u1.w;
    }
    __syncthreads();

    for (int k = 0; k < 32; k += 4) {
      float a0, a1, a2, a3;
      if (AMODE == 0) {
        const float* ap = AT + (size_t)(kc + k) * 64 + lane;
        a0 = ap[0]; a1 = ap[64]; a2 = ap[128]; a3 = ap[192];
      } else if (AMODE == 2) {
        const float4 u = *(const float4*)(Af + (size_t)(m0 + lane) * K + kc + k);
        a0 = u.x; a1 = u.y; a2 = u.z; a3 = u.w;
      } else {
        int kg = kc + k;
        a0 = xfetch(kg + 0); a1 = xfetch(kg + 1);
        a2 = xfetch(kg + 2); a3 = xfetch(kg + 3);
      }
      const float* wr = &Ws[(wv * 16) * 36 + k];
#pragma unroll
      for (int j = 0; j < 16; ++j) {
        float4 w = *(const float4*)(wr + j * 36);
        acc[j] = fmaf(w.x, a0, acc[j]);
        acc[j] = fmaf(w.y, a1, acc[j]);
        acc[j] = fmaf(w.z, a2, acc[j]);
        acc[j] = fmaf(w.w, a3, acc[j]);
      }
    }
    __syncthreads();
  }

  const int nbase = n0 + wv * 16;
  if (OUTMODE == 0) {
    float* cb = Cout + (size_t)blockIdx.z * zstride;
#pragma unroll
    for (int j = 0; j < 16; ++j) {
      float c = acc[j];
      if (bias) c += bias[nbase + j];
      cb[(size_t)(nbase + j) * c_sn + (size_t)(m0 + lane) * c_sm] = c;
    }
  } else {
    float vmax = -__builtin_inff(); float s = 0.f; int vidx = 0x7fffffff;
    float ob[16];
#pragma unroll
    for (int j = 0; j < 16; ++j) {
      float c = acc[j] + bias[nbase + j];
      ob[j] = c;
      if (c > vmax) { s = s * __expf(vmax - c) + 1.f; vmax = c; vidx = nbase + j; }
      else          { s += __expf(c - vmax); }
    }
    float* op = out2 + (size_t)lane * (T_ * V_) + (size_t)t * V_ + nbase;
    float4 q0, q1, q2, q3;
    q0.x = ob[0];  q0.y = ob[1];  q0.z = ob[2];  q0.w = ob[3];
    q1.x = ob[4];  q1.y = ob[5];  q1.z = ob[6];  q1.w = ob[7];
    q2.x = ob[8];  q2.y = ob[9];  q2.z = ob[10]; q2.w = ob[11];
    q3.x = ob[12]; q3.y = ob[13]; q3.z = ob[14]; q3.w = ob[15];
    ((float4*)op)[0] = q0; ((float4*)op)[1] = q1;
    ((float4*)op)[2] = q2; ((float4*)op)[3] = q3;
    int pb = (blockIdx.x * 4 + wv) * 64 + lane;
    pmax[pb] = vmax; psum[pb] = s; pidx[pb] = vidx;
  }
}

// ---------------------------------------------------------------------------
__global__ __launch_bounds__(256) void gru_combine(
    const float* __restrict__ gip, const float* __restrict__ ghp,
    const float* __restrict__ b_ih, const float* __restrict__ b_hh,
    float* __restrict__ chT)
{
  int tgl = blockIdx.x * 256 + threadIdx.x;   // 64*1024
  int b = tgl & 63; int i = tgl >> 6;
  float ir = b_ih[i], iz = b_ih[H_ + i], in_ = b_ih[2 * H_ + i];
  float hr = b_hh[i], hz = b_hh[H_ + i], hn  = b_hh[2 * H_ + i];
  for (int kz = 0; kz < 13; ++kz) {
    const float* p = gip + (size_t)kz * (3 * H_ * 64);
    ir  += p[(size_t)i * 64 + b];
    iz  += p[(size_t)(H_ + i) * 64 + b];
    in_ += p[(size_t)(2 * H_ + i) * 64 + b];
  }
  for (int kz = 0; kz < 8; ++kz) {
    const float* p = ghp + (size_t)kz * (3 * H_ * 64);
    hr += p[(size_t)i * 64 + b];
    hz += p[(size_t)(H_ + i) * 64 + b];
    hn += p[(size_t)(2 * H_ + i) * 64 + b];
  }
  float r = 1.f / (1.f + expf(-(ir + hr)));
  float z = 1.f / (1.f + expf(-(iz + hz)));
  float n = tanhf(in_ + r * hn);
  float h = chT[(size_t)(H_ + i) * 64 + b];
  chT[(size_t)(H_ + i) * 64 + b] = (1.f - z) * n + z * h;
}

__global__ __launch_bounds__(256) void o_combine(
    const float* __restrict__ op, const float* __restrict__ b1,
    float* __restrict__ oT)
{
  int tgl = blockIdx.x * 256 + threadIdx.x;   // 64*1024
  int b = tgl & 63; int i = tgl >> 6;
  float v = b1[i];
  for (int kz = 0; kz < 8; ++kz) v += op[(size_t)kz * (H_ * 64) + (size_t)i * 64 + b];
  v = (v >= 0.f) ? v : 0.1f * v;   // LeakyReLU(0.1)
  oT[(size_t)i * 64 + b] = v;
}

// ---------------------------------------------------------------------------
// Fused: q = h@Wq^T + bq ; additive-coverage energies ; masked softmax ;
// attn out (f32) ; cov += attn ; ctx = attn @ enc -> chT rows [0,1024)
// One block per batch element.
// ---------------------------------------------------------------------------
__global__ __launch_bounds__(256) void attn_kernel(
    float* __restrict__ chT, const float* __restrict__ kp, float* __restrict__ cov,
    const float* __restrict__ Wq, const float* __restrict__ bq,
    const float* __restrict__ Wc, const float* __restrict__ Wo,
    const float* __restrict__ enc, const int* __restrict__ enc_len,
    float* __restrict__ out_attn, int t)
{
  __shared__ float h_s[H_], q_s[ATT_], Wc_s[ATT_], Wo_s[ATT_];
  __shared__ float cov_s[L_], e_s[L_], a_s[L_];
  int b = blockIdx.x; int tid = threadIdx.x;

  for (int i = tid; i < H_; i += 256) h_s[i] = chT[(size_t)(H_ + i) * 64 + b];
  for (int i = tid; i < ATT_; i += 256) { Wc_s[i] = Wc[i]; Wo_s[i] = Wo[i]; }
  if (tid < L_) cov_s[tid] = cov[b * L_ + tid];
  __syncthreads();

  for (int a = tid; a < ATT_; a += 256) {
    float accq = bq[a];
    const float* wr = Wq + (size_t)a * H_;
    for (int k = 0; k < H_; k += 4) {
      float4 u = *(const float4*)(wr + k);
      accq = fmaf(u.x, h_s[k + 0], accq);
      accq = fmaf(u.y, h_s[k + 1], accq);
      accq = fmaf(u.z, h_s[k + 2], accq);
      accq = fmaf(u.w, h_s[k + 3], accq);
    }
    q_s[a] = accq;
  }
  __syncthreads();

  int lane = tid & 63, wv = tid >> 6;
  int elen = enc_len[b];
  for (int l = wv; l < L_; l += 4) {
    float e = 0.f;
    const float* kpr = kp + ((size_t)b * L_ + l) * ATT_;
    float cv = cov_s[l];
    for (int a = lane; a < ATT_; a += 64)
      e += tanhf(q_s[a] + kpr[a] + cv * Wc_s[a]) * Wo_s[a];
#pragma unroll
    for (int off = 32; off > 0; off >>= 1) e += __shfl_down(e, off);
    if (lane == 0) e_s[l] = (l < elen) ? e : -1e10f;
  }
  __syncthreads();

  if (tid < L_) {
    float v = e_s[tid];
    float mx = v;
#pragma unroll
    for (int off = 32; off > 0; off >>= 1) mx = fmaxf(mx, __shfl_xor(mx, off));
    float ex = expf(v - mx);
    float sm = ex;
#pragma unroll
    for (int off = 32; off > 0; off >>= 1) sm += __shfl_xor(sm, off);
    float at = ex / sm;
    a_s[tid] = at;
    cov[b * L_ + tid] = cov_s[tid] + at;
    out_attn[((size_t)b * T_ + t) * L_ + tid] = at;
  }
  __syncthreads();

  for (int d = tid; d < ENC_; d += 256) {
    float accc = 0.f;
    for (int l = 0; l < L_; ++l)
      accc = fmaf(a_s[l], enc[((size_t)b * L_ + l) * ENC_ + d], accc);
    chT[(size_t)d * 64 + b] = accc;   // ctx rows [0, 1024)
  }
}

// ---------------------------------------------------------------------------
__global__ __launch_bounds__(64) void lse_final(
    const float* __restrict__ pmax, const float* __restrict__ psum,
    const int* __restrict__ pidx,
    float* __restrict__ out, int* __restrict__ previ, int t)
{
  int b = blockIdx.x; int lane = threadIdx.x;
  float vmax = -__builtin_inff(); int vidx = 0x7fffffff;
  for (int p = lane; p < 2000; p += 64) {
    float v = pmax[(size_t)p * 64 + b]; int i = pidx[(size_t)p * 64 + b];
    if (v > vmax || (v == vmax && i < vidx)) { vmax = v; vidx = i; }
  }
#pragma unroll
  for (int off = 32; off > 0; off >>= 1) {
    float ov = __shfl_xor(vmax, off); int oi = __shfl_xor(vidx, off);
    if (ov > vmax || (ov == vmax && oi < vidx)) { vmax = ov; vidx = oi; }
  }
  float s = 0.f;
  for (int p = lane; p < 2000; p += 64)
    s += psum[(size_t)p * 64 + b] * __expf(pmax[(size_t)p * 64 + b] - vmax);
#pragma unroll
  for (int off = 32; off > 0; off >>= 1) s += __shfl_xor(s, off);
  if (lane == 0) {
    if (vidx < 0 || vidx >= V_) vidx = 0;           // defensive clamp
    out[DEC_OFF  + b * T_ + t] = -logf(s);          // logit[pred]=max -> max-LSE
    out[PRED_OFF + b * T_ + t] = (float)vidx;       // exact: vidx < 2^24
    previ[b] = vidx;
  }
}

__global__ __launch_bounds__(256) void init_state(float* chT, float* cov, int* previ)
{
  int tgl = blockIdx.x * 256 + threadIdx.x;
  if (tgl < 2048 * 64) chT[tgl] = 0.f;
  else if (tgl < 2048 * 64 + 64 * 64) cov[tgl - 2048 * 64] = 0.f;
  else if (tgl < 2048 * 64 + 64 * 64 + 64) previ[tgl - (2048 * 64 + 64 * 64)] = 1; // BOS
}

// ---------------------------------------------------------------------------
extern "C" void kernel_launch(void* const* d_in, const int* in_sizes, int n_in,
                              void* d_out, int out_size, void* d_ws, size_t ws_size,
                              hipStream_t stream)
{
  const float* enc     = (const float*)d_in[0];
  const int*   enc_len = (const int*)d_in[1];
  const int*   styles  = (const int*)d_in[2];
  const float* emb     = (const float*)d_in[3];
  const float* stab    = (const float*)d_in[4];
  const float* Wq      = (const float*)d_in[5];
  const float* bq      = (const float*)d_in[6];
  const float* Wk      = (const float*)d_in[7];
  const float* Wc      = (const float*)d_in[8];
  const float* Wo      = (const float*)d_in[9];
  const float* W_ih    = (const float*)d_in[10];
  const float* b_ih    = (const float*)d_in[11];
  const float* W_hh    = (const float*)d_in[12];
  const float* b_hh    = (const float*)d_in[13];
  const float* W1      = (const float*)d_in[14];
  const float* b1      = (const float*)d_in[15];
  const float* W2      = (const float*)d_in[16];
  const float* b2      = (const float*)d_in[17];
  float* out = (float*)d_out;

  char* ws = (char*)d_ws;
  float* kp   = (float*)(ws + 0);          // [4096][512] f32  keys_proj[m][a]
  float* chT  = (float*)(ws + 8388608);    // [2048][64]  ctx rows 0..1023 | h rows 1024..2047
  float* cov  = (float*)(ws + 8912896);    // [64][64]
  float* gi_p = (float*)(ws + 8929280);    // [13][3072][64]
  float* gh_p = (float*)(ws + 19152896);   // [8][3072][64]
  float* o_p  = (float*)(ws + 25444352);   // [8][1024][64]
  float* oT   = (float*)(ws + 27541504);   // [1024][64]
  float* pmax = (float*)(ws + 27803648);   // [2000][64]
  float* psum = (float*)(ws + 28315648);   // [2000][64]
  int*   pidx = (int*)  (ws + 28827648);   // [2000][64]
  int*   prev = (int*)  (ws + 29339648);   // [64]

  init_state<<<529, 256, 0, stream>>>(chT, cov, prev);

  // keys_proj (hoisted): kp[b*64+l][a] = enc[b,l,:] . Wk[a,:]
  gemm_b<2, 0><<<dim3(8, 64, 1), 256, 0, stream>>>(
      Wk, ATT_, ENC_, ENC_,
      nullptr, enc, nullptr, nullptr, nullptr, nullptr, nullptr,
      kp, 0, /*c_sn=*/1, /*c_sm=*/ATT_, nullptr, 0, nullptr, nullptr, nullptr);

  for (int t = 0; t < T_; ++t) {
    // gi = x @ W_ih^T (x gathered: emb[prev] | style | ctx), K=1664, 13 K-splits
    gemm_b<1, 0><<<dim3(48, 1, 13), 256, 0, stream>>>(
        W_ih, 3 * H_, 1664, 128,
        nullptr, emb, stab, prev, styles, chT, nullptr,
        gi_p, (size_t)3 * H_ * 64, 64, 1, nullptr, 0, nullptr, nullptr, nullptr);
    // gh = h @ W_hh^T, K=1024, 8 K-splits
    gemm_b<0, 0><<<dim3(48, 1, 8), 256, 0, stream>>>(
        W_hh, 3 * H_, H_, 128,
        chT + (size_t)H_ * 64, nullptr, nullptr, nullptr, nullptr, nullptr, nullptr,
        gh_p, (size_t)3 * H_ * 64, 64, 1, nullptr, 0, nullptr, nullptr, nullptr);
    gru_combine<<<256, 256, 0, stream>>>(gi_p, gh_p, b_ih, b_hh, chT);
    attn_kernel<<<64, 256, 0, stream>>>(chT, kp, cov, Wq, bq, Wc, Wo, enc, enc_len,
                                        out + ATT_OFF, t);
    // o_pre = [ctx|h] @ W1^T, K=2048, 8 K-splits
    gemm_b<0, 0><<<dim3(16, 1, 8), 256, 0, stream>>>(
        W1, H_, 2 * H_, 256,
        chT, nullptr, nullptr, nullptr, nullptr, nullptr, nullptr,
        o_p, (size_t)H_ * 64, 64, 1, nullptr, 0, nullptr, nullptr, nullptr);
    o_combine<<<256, 256, 0, stream>>>(o_p, b1, oT);
    // logits = o @ W2^T + b2 : fused f32 logits out + online LSE/argmax partials
    gemm_b<0, 1><<<dim3(500, 1, 1), 256, 0, stream>>>(
        W2, V_, H_, H_,
        oT, nullptr, nullptr, nullptr, nullptr, nullptr, b2,
        nullptr, 0, 0, 0, out, t, pmax, psum, pidx);
    lse_final<<<64, 64, 0, stream>>>(pmax, psum, pidx, out, prev, t);
  }
}